// Round 3
// baseline (271.899 us; speedup 1.0000x reference)
//
#include <hip/hip_runtime.h>
#include <hip/hip_bf16.h>
#include <cstddef>

#define SB 4
#define SS 2048
#define SH 1024
#define NH 16
#define HD 64
#define WIN 256

typedef __attribute__((ext_vector_type(8))) short bf16x8;
typedef __attribute__((ext_vector_type(8))) _Float16 f16x8;
typedef __attribute__((ext_vector_type(2))) __fp16 fp16v2;
typedef __attribute__((ext_vector_type(4))) float f32x4;

static __device__ __forceinline__ ushort2 pk_bf16(float a, float b) {
    __hip_bfloat162 h = __float22bfloat162_rn(make_float2(a, b));
    union { __hip_bfloat162 h2; ushort2 u2; } u;
    u.h2 = h;
    return u.u2;
}
static __device__ __forceinline__ unsigned short pk1(float a) {
    return pk_bf16(a, 0.f).x;
}

// Async global->LDS, 16B per lane. LDS dest is wave-uniform base + lane*16
// (m104/m108): pass the SAME lds pointer from every lane of a wave.
static __device__ __forceinline__ void async16(const void* gptr, void* lptr) {
    __builtin_amdgcn_global_load_lds(
        (const __attribute__((address_space(1))) unsigned int*)gptr,
        (__attribute__((address_space(3))) unsigned int*)lptr, 16, 0, 0);
}

// Compiler-only memory fence: stops hipcc moving LDS/global accesses across
// barrier points (s_barrier builtin is NOT a compiler fence).
#define CFENCE() asm volatile("" ::: "memory")

// All six fp32->f16 conversions in one launch.
__global__ __launch_bounds__(256) void cvt_all(
    const float* __restrict__ x,  const float* __restrict__ xc,
    const float* __restrict__ Wq, const float* __restrict__ Wk,
    const float* __restrict__ Wv, const float* __restrict__ Wo,
    _Float16* __restrict__ xh,  _Float16* __restrict__ xch,
    _Float16* __restrict__ Wqh, _Float16* __restrict__ Wkh,
    _Float16* __restrict__ Wvh, _Float16* __restrict__ Woh)
{
    const int I4 = SB * SS * SH / 4;       // 2^21
    const int W4 = SH * SH / 4;            // 2^18
    int idx = blockIdx.x * 256 + threadIdx.x;
    const float* src;
    _Float16* dst;
    int off;
    if (idx < I4) { src = x; dst = xh; off = idx; }
    else if (idx < 2 * I4) { src = xc; dst = xch; off = idx - I4; }
    else {
        int r = idx - 2 * I4;
        int wi = r >> 18;
        off = r & (W4 - 1);
        src = (wi == 0) ? Wq : (wi == 1) ? Wk : (wi == 2) ? Wv : Wo;
        dst = (wi == 0) ? Wqh : (wi == 1) ? Wkh : (wi == 2) ? Wvh : Woh;
    }
    float4 v = ((const float4*)src)[off];
    union { fp16v2 h[2]; uint2 u; } t;
    t.h[0] = __builtin_amdgcn_cvt_pkrtz(v.x, v.y);
    t.h[1] = __builtin_amdgcn_cvt_pkrtz(v.z, v.w);
    ((uint2*)dst)[off] = t.u;
}

// ---------------------------------------------------------------------------
// 8-phase GEMM core (m201 template, parameterized BM=128, BN=256, BK=64).
// C[M,N] = A[M,K] @ W[N,K]^T, f16 operands, fp32 acc.
// 512 threads = 8 waves (2M x 4N), per-wave output 64x64 (4x4 fragments).
// LDS 96KB: A[2buf][128][64] + B[2buf][256][64] f16.
//
// Bank-conflict swizzle (G4/m214 form, FULL 3-bit): rows are 128B = 8 x 16B
// slots; an MFMA ds_read_b128 has 16 lanes reading 16 rows at one slot ->
// 16-way conflict unswizzled. Fix: byte ^= (row&7)<<4, i.e. element col
// ^= (lrow&7)<<3 -> 8-row stripe spreads over all 8 slots, 2 lanes/slot
// (free, m136). Round-2's single-bit (row&4) variant left 8-way conflicts
// (counter 6.5M, unchanged) - this is the corrected both-sides version:
// linear gload_lds dest + inverse-permuted GLOBAL source col
// ((lane&7)^((lane>>3)&7))<<3 (each issue covers exactly 8 rows,
// row-within-issue = lane>>3) + swizzled ds_read col.
//
// Per K-tile 4 phases, counted vmcnt(4) only at tile boundary, raw
// s_barrier, setprio(1) around MFMA. Stage placement region-lifetime safe:
//   A(t+1) -> opposite buffer (idle during tile t)      [P1,P2]
//   B(t+2) -> current buffer, B last read at P2, staged at P3/P4 (after
//             P2's trailing barrier => every wave's B reads complete).
// vmcnt ledger: 6 issues/tile (1+1+2+2); boundary vmcnt(4) keeps exactly
// B(t+2) in flight; prologue 10 issues, vmcnt(4) keeps B(1) in flight.
// ---------------------------------------------------------------------------
static __device__ __forceinline__ void gemm8_core(
    const _Float16* __restrict__ A, const _Float16* __restrict__ W,
    int m0, int n0, unsigned short* __restrict__ smem, f32x4 (&acc)[4][4])
{
    const int K = SH;
    const int NT = K / 64;                 // 16 K-tiles
    const int tid = threadIdx.x;
    const int w = tid >> 6, lane = tid & 63;
    const int wm = (w >> 2) * 64;          // wave row origin (0/64)
    const int wn = (w & 3) * 64;           // wave col origin (0/64/128/192)
    const int lrow = lane & 15;
    const int lk8 = (lane >> 4) * 8;
    const int swz = (lrow & 7) << 3;       // element-XOR: slot ^= row&7

    // staging lane geometry: one issue = 8 rows x 128B per wave (1KB);
    // inverse-permuted source col so linear LDS dest + swizzled read match.
    const int srow = w * 8 + (lane >> 3);                          // 0..63
    const int scol = ((lane & 7) ^ ((lane >> 3) & 7)) << 3;        // src col elems
    const _Float16* aS = A + (size_t)(m0 + srow) * K + scol;
    const _Float16* bS = W + (size_t)(n0 + srow) * K + scol;

    auto stA = [&](int tile, int half) {   // A half = 64 rows = 1 issue
        async16(aS + (size_t)(half * 64) * K + tile * 64,
                smem + ((tile & 1) << 13) + half * 4096 + w * 512);
    };
    auto stB = [&](int tile, int half) {   // B half = 128 rows = 2 issues
        async16(bS + (size_t)(half * 128) * K + tile * 64,
                smem + 16384 + ((tile & 1) << 14) + half * 8192 + w * 512);
        async16(bS + (size_t)(half * 128 + 64) * K + tile * 64,
                smem + 16384 + ((tile & 1) << 14) + half * 8192 + 4096 + w * 512);
    };

    f16x8 a[2][2];        // current A half-frags   [m][ks]
    f16x8 b[2][2][2];     // full B tile frags      [nh][n][ks]

    // Prologue: tile0 fully + tile1's B. vmcnt(4) => tile0 landed, tile1 B flies.
    stA(0, 0); stA(0, 1);
    stB(0, 0); stB(0, 1);
    stB(1, 0); stB(1, 1);
    asm volatile("s_waitcnt vmcnt(4)" ::: "memory");
    __builtin_amdgcn_s_barrier();
    CFENCE();

    for (int t = 0; t < NT; ++t) {
        const int cur = t & 1;
        unsigned short* LA = smem + (cur << 13);
        unsigned short* LB = smem + 16384 + (cur << 14);

        // ---- P1: read A(mh0) + B(nh0); stage A(t+1) h0; MFMA Q(0,0)
#pragma unroll
        for (int m = 0; m < 2; ++m)
#pragma unroll
            for (int ks = 0; ks < 2; ++ks)
                a[m][ks] = *(const f16x8*)(LA + (wm + m * 16 + lrow) * 64 + ((ks * 32 + lk8) ^ swz));
#pragma unroll
        for (int n = 0; n < 2; ++n)
#pragma unroll
            for (int ks = 0; ks < 2; ++ks)
                b[0][n][ks] = *(const f16x8*)(LB + (wn + n * 16 + lrow) * 64 + ((ks * 32 + lk8) ^ swz));
        if (t + 1 < NT) stA(t + 1, 0);
        CFENCE();
        __builtin_amdgcn_s_barrier();
        CFENCE();
        asm volatile("s_waitcnt lgkmcnt(0)" ::: "memory");
        __builtin_amdgcn_s_setprio(1);
#pragma unroll
        for (int ks = 0; ks < 2; ++ks)
#pragma unroll
            for (int m = 0; m < 2; ++m)
#pragma unroll
                for (int n = 0; n < 2; ++n)
                    acc[m][n] = __builtin_amdgcn_mfma_f32_16x16x32_f16(a[m][ks], b[0][n][ks], acc[m][n], 0, 0, 0);
        __builtin_amdgcn_s_setprio(0);
        CFENCE();
        __builtin_amdgcn_s_barrier();
        CFENCE();

        // ---- P2: read B(nh1); stage A(t+1) h1; MFMA Q(0,1)
#pragma unroll
        for (int n = 0; n < 2; ++n)
#pragma unroll
            for (int ks = 0; ks < 2; ++ks)
                b[1][n][ks] = *(const f16x8*)(LB + (wn + 32 + n * 16 + lrow) * 64 + ((ks * 32 + lk8) ^ swz));
        if (t + 1 < NT) stA(t + 1, 1);
        CFENCE();
        __builtin_amdgcn_s_barrier();
        CFENCE();
        asm volatile("s_waitcnt lgkmcnt(0)" ::: "memory");
        __builtin_amdgcn_s_setprio(1);
#pragma unroll
        for (int ks = 0; ks < 2; ++ks)
#pragma unroll
            for (int m = 0; m < 2; ++m)
#pragma unroll
                for (int n = 0; n < 2; ++n)
                    acc[m][2 + n] = __builtin_amdgcn_mfma_f32_16x16x32_f16(a[m][ks], b[1][n][ks], acc[m][2 + n], 0, 0, 0);
        __builtin_amdgcn_s_setprio(0);
        CFENCE();
        __builtin_amdgcn_s_barrier();
        CFENCE();

        // ---- P3: read A(mh1); stage B(t+2) h0; MFMA Q(1,1)
#pragma unroll
        for (int m = 0; m < 2; ++m)
#pragma unroll
            for (int ks = 0; ks < 2; ++ks)
                a[m][ks] = *(const f16x8*)(LA + (wm + 32 + m * 16 + lrow) * 64 + ((ks * 32 + lk8) ^ swz));
        if (t + 2 < NT) stB(t + 2, 0);
        CFENCE();
        __builtin_amdgcn_s_barrier();
        CFENCE();
        asm volatile("s_waitcnt lgkmcnt(0)" ::: "memory");
        __builtin_amdgcn_s_setprio(1);
#pragma unroll
        for (int ks = 0; ks < 2; ++ks)
#pragma unroll
            for (int m = 0; m < 2; ++m)
#pragma unroll
                for (int n = 0; n < 2; ++n)
                    acc[2 + m][2 + n] = __builtin_amdgcn_mfma_f32_16x16x32_f16(a[m][ks], b[1][n][ks], acc[2 + m][2 + n], 0, 0, 0);
        __builtin_amdgcn_s_setprio(0);
        CFENCE();
        __builtin_amdgcn_s_barrier();
        CFENCE();

        // ---- P4: stage B(t+2) h1; MFMA Q(1,0); boundary counted vmcnt
        if (t + 2 < NT) stB(t + 2, 1);
        CFENCE();
        __builtin_amdgcn_s_barrier();
        CFENCE();
        __builtin_amdgcn_s_setprio(1);
#pragma unroll
        for (int ks = 0; ks < 2; ++ks)
#pragma unroll
            for (int m = 0; m < 2; ++m)
#pragma unroll
                for (int n = 0; n < 2; ++n)
                    acc[2 + m][n] = __builtin_amdgcn_mfma_f32_16x16x32_f16(a[m][ks], b[0][n][ks], acc[2 + m][n], 0, 0, 0);
        __builtin_amdgcn_s_setprio(0);
        // Boundary: allow the 4 newest loads (B(t+2), P3+P4) to stay in flight.
        if (t < NT - 2) asm volatile("s_waitcnt vmcnt(4)" ::: "memory");
        else            asm volatile("s_waitcnt vmcnt(0)" ::: "memory");
        __builtin_amdgcn_s_barrier();
        CFENCE();
    }
    CFENCE();
}

// Fused Q/K/V projection GEMMs, 8-phase core. blockIdx.z picks {A, W, epilogue}.
// z=0: x@Wq -> Qh (f16); z=1: xc@Wk -> Kh (f16); z=2: xc@Wv -> Vt (bf16, C^T).
__global__ __launch_bounds__(512, 2) void gemm_qkv8(
    const _Float16* __restrict__ xh, const _Float16* __restrict__ xch,
    const _Float16* __restrict__ Wqh, const _Float16* __restrict__ Wkh,
    const _Float16* __restrict__ Wvh,
    _Float16* __restrict__ Qh, _Float16* __restrict__ Kh,
    unsigned short* __restrict__ Vt)
{
    __shared__ __align__(16) unsigned short smem[49152]; // 96KB
    const int z = blockIdx.z;
    const _Float16* A = (z == 0) ? xh : xch;
    const _Float16* W = (z == 0) ? Wqh : (z == 1) ? Wkh : Wvh;
    const int m0 = blockIdx.x * 128;
    const int n0 = blockIdx.y * 256;

    f32x4 acc[4][4];
#pragma unroll
    for (int i = 0; i < 4; ++i)
#pragma unroll
        for (int j = 0; j < 4; ++j)
            acc[i][j] = (f32x4){0.f, 0.f, 0.f, 0.f};

    gemm8_core(A, W, m0, n0, smem, acc);

    const int tid = threadIdx.x;
    const int w = tid >> 6, lane = tid & 63;
    const int wm = (w >> 2) * 64, wn = (w & 3) * 64;
    const int lrow = lane & 15;
    const int rq = (lane >> 4) * 4;
    const int M = SB * SS, N = SH;

    // C/D layout: col = lane&15, row = (lane>>4)*4 + reg.
    if (z < 2) {
        // f16 out via full-tile LDS transpose (128 x 264) -> b128 stores.
        _Float16* C = (z == 0) ? Qh : Kh;
        _Float16* T = (_Float16*)smem;
#pragma unroll
        for (int m = 0; m < 4; ++m)
#pragma unroll
            for (int n = 0; n < 4; ++n)
#pragma unroll
                for (int r = 0; r < 4; ++r)
                    T[(wm + m * 16 + rq + r) * 264 + wn + n * 16 + lrow] = (_Float16)acc[m][n][r];
        __syncthreads();
#pragma unroll
        for (int u = 0; u < 8; ++u) {
            int slot = u * 512 + tid;              // 4096 uint4 slots
            int row = slot >> 5;
            int c8 = (slot & 31) * 8;
            *(uint4*)(C + (size_t)(m0 + row) * N + n0 + c8) =
                *(const uint4*)&T[row * 264 + c8];
        }
    } else {
        // Transposed bf16 out via LDS (256 x 136 shorts), single pass.
        unsigned short* T = smem;
#pragma unroll
        for (int n = 0; n < 4; ++n)
#pragma unroll
            for (int m = 0; m < 4; ++m) {
                int rt = wn + n * 16 + lrow;
                *(ushort4*)&T[rt * 136 + wm + m * 16 + rq] = make_ushort4(
                    pk1(acc[m][n][0]), pk1(acc[m][n][1]),
                    pk1(acc[m][n][2]), pk1(acc[m][n][3]));
            }
        __syncthreads();
#pragma unroll
        for (int u = 0; u < 8; ++u) {
            int slot = u * 512 + tid;              // 4096 uint4 slots
            int row = slot >> 4;
            int m8 = (slot & 15) * 8;
            *(uint4*)(Vt + (size_t)(n0 + row) * M + m0 + m8) =
                *(const uint4*)&T[row * 136 + m8];
        }
    }
}

// O-projection GEMM: ctx(f16) @ Wo^T + bo -> out (fp32), 8-phase core,
// direct fp32 stores (4x64B segments per instr).
__global__ __launch_bounds__(512, 2) void gemm_o8(
    const _Float16* __restrict__ A, const _Float16* __restrict__ W,
    const float* __restrict__ bias, float* __restrict__ C)
{
    __shared__ __align__(16) unsigned short smem[49152]; // 96KB
    const int m0 = blockIdx.x * 128;
    const int n0 = blockIdx.y * 256;

    f32x4 acc[4][4];
#pragma unroll
    for (int i = 0; i < 4; ++i)
#pragma unroll
        for (int j = 0; j < 4; ++j)
            acc[i][j] = (f32x4){0.f, 0.f, 0.f, 0.f};

    gemm8_core(A, W, m0, n0, smem, acc);

    const int tid = threadIdx.x;
    const int w = tid >> 6, lane = tid & 63;
    const int wm = (w >> 2) * 64, wn = (w & 3) * 64;
    const int lrow = lane & 15;
    const int rq = (lane >> 4) * 4;
    const int N = SH;

#pragma unroll
    for (int m = 0; m < 4; ++m) {
        int rbase = m0 + wm + m * 16 + rq;
#pragma unroll
        for (int n = 0; n < 4; ++n) {
            int col = n0 + wn + n * 16 + lrow;
            float badd = bias[col];
#pragma unroll
            for (int r = 0; r < 4; ++r)
                C[(size_t)(rbase + r) * N + col] = acc[m][n][r] + badd;
        }
    }
}

// MFMA flash attention, local causal window. Block = 8 waves = 256 queries of
// one (b,h): halves barriers and K/V staging per query vs 128-query blocks.
// Double-buffered K/V chunks (stage c+1 during compute of c); waves skip
// chunks outside their 287-key window (wave-uniform branch). 1-D grid with
// id%8 == (h,b)-pair%8 so all qb-blocks of one (b,h) share one XCD's L2
// (K+V per pair = 512KB; 8 pairs/XCD = 4MB = L2 size). P,V bf16 (exp(s) up
// to ~e^47 needs bf16 range; no online max since fp32 can't overflow).
// ctx may alias Qg: each wave reads exactly the 32 Q rows it later writes,
// reads happen before any write, rows are wave-exclusive -> race-free.
__global__ __launch_bounds__(512, 4) void attn5(
    const _Float16* Qg, const _Float16* __restrict__ Kg,
    const unsigned short* __restrict__ Vtg, const float* __restrict__ amask,
    _Float16* ctxg)
{
    __shared__ __align__(16) _Float16 K_s[2][2 * 64 * 32];        // 16KB [buf][ki][key][32d]
    __shared__ __align__(16) unsigned short V_s[2][2 * 64 * 32];  // 16KB [buf][ki][d][32key]
    __shared__ __align__(16) unsigned short P_s[8][32 * 72];      // 36.9KB per-wave strips

    const int t = threadIdx.x;
    const int wave = t >> 6, lane = t & 63;
    const int id = blockIdx.x;        // 512 blocks
    const int qb = id >> 6;           // 0..7
    const int pr = id & 63;           // (h,b) pair; id%8 = pr%8 -> XCD grouping
    const int h = pr & 15, b = pr >> 4;
    const int t0 = qb * 256;
    const int wq = t0 + wave * 32;    // this wave's first query
    const int lrow = lane & 15;
    const int lk8 = (lane >> 4) * 8;
    const int rq = (lane >> 4) * 4;
    const int M = SB * SS;
    unsigned short* P = P_s[wave];

    // Staging decomposition: 512 threads x 16B = one full 8KB chunk per array.
    const int ski = t >> 8;           // ki half
    const int srow = (t & 255) >> 2;  // key row (K) / d row (Vt)
    const int se8 = (t & 3) * 8;

    // Q A-fragments in registers (wave-private rows).
    f16x8 qf[2][2];
#pragma unroll
    for (int i = 0; i < 2; ++i)
#pragma unroll
        for (int ki = 0; ki < 2; ++ki)
            qf[i][ki] = *(const f16x8*)(Qg +
                (size_t)(b * SS + wq + i * 16 + lrow) * SH + h * HD + ki * 32 + lk8);

    f32x4 o[2][4];
    float lsum[2][4];
#pragma unroll
    for (int i = 0; i < 2; ++i)
#pragma unroll
        for (int j = 0; j < 4; ++j) o[i][j] = (f32x4){0.f, 0.f, 0.f, 0.f};
#pragma unroll
    for (int i = 0; i < 2; ++i)
#pragma unroll
        for (int r = 0; r < 4; ++r) lsum[i][r] = 0.f;

    int cl0 = t0 - (WIN - 1);
    cl0 = cl0 < 0 ? 0 : cl0;
    const int c_lo = cl0 >> 6;
    const int c_hi = (t0 >> 6) + 3;   // keys up to t0+255

    auto stage = [&](int c, int buf) {
        const int key0 = c * 64;
        async16(Kg + (size_t)(b * SS + key0 + srow) * SH + h * HD + ski * 32 + se8,
                (_Float16*)K_s[buf] + wave * 512);
        async16(Vtg + (size_t)(h * HD + srow) * M + b * SS + key0 + ski * 32 + se8,
                (unsigned short*)V_s[buf] + wave * 512);
    };

    stage(c_lo, c_lo & 1);
    __syncthreads();

    for (int c = c_lo; c <= c_hi; ++c) {
        const int cur = c & 1;
        if (c < c_hi) stage(c + 1, cur ^ 1);     // flies during compute below
        const int key0 = c * 64;
        // Wave-uniform skip: does chunk intersect this wave's key window?
        if (key0 <= wq + 31 && key0 + 63 >= wq - (WIN - 1)) {
            const _Float16* Kc = (const _Float16*)K_s[cur];
            const unsigned short* Vc = (const unsigned short*)V_s[cur];

            // S = Q @ K^T
            f32x4 s[2][4];
#pragma unroll
            for (int i = 0; i < 2; ++i)
#pragma unroll
                for (int j = 0; j < 4; ++j) s[i][j] = (f32x4){0.f, 0.f, 0.f, 0.f};
#pragma unroll
            for (int ki = 0; ki < 2; ++ki)
#pragma unroll
                for (int j = 0; j < 4; ++j) {
                    f16x8 bh = *(const f16x8*)&Kc[ki * 2048 + (j * 16 + lrow) * 32 + lk8];
#pragma unroll
                    for (int i = 0; i < 2; ++i)
                        s[i][j] = __builtin_amdgcn_mfma_f32_16x16x32_f16(qf[i][ki], bh, s[i][j], 0, 0, 0);
                }

            // mask + exp (fp32), row-sum partials, P -> bf16 LDS (A-layout rows).
#pragma unroll
            for (int i = 0; i < 2; ++i)
#pragma unroll
                for (int j = 0; j < 4; ++j) {
                    int jg = key0 + j * 16 + lrow;
#pragma unroll
                    for (int r = 0; r < 4; ++r) {
                        int qg = wq + i * 16 + rq + r;
                        float p = (jg <= qg && jg > qg - WIN) ? __expf(s[i][j][r]) : 0.f;
                        lsum[i][r] += p;
                        P[(i * 16 + rq + r) * 72 + j * 16 + lrow] = pk1(p);
                    }
                }

            // ctx += P @ V (in-wave LDS dependency only)
#pragma unroll
            for (int ki = 0; ki < 2; ++ki) {
                bf16x8 pf[2];
#pragma unroll
                for (int i = 0; i < 2; ++i)
                    pf[i] = *(const bf16x8*)&P[(i * 16 + lrow) * 72 + ki * 32 + lk8];
#pragma unroll
                for (int j = 0; j < 4; ++j) {
                    bf16x8 vf = *(const bf16x8*)&Vc[ki * 2048 + (j * 16 + lrow) * 32 + lk8];
#pragma unroll
                    for (int i = 0; i < 2; ++i)
                        o[i][j] = __builtin_amdgcn_mfma_f32_16x16x32_bf16(pf[i], vf, o[i][j], 0, 0, 0);
                }
            }
        }
        __syncthreads();   // guards buffers; drains in-flight staging
    }

    // Row sums: 4 xor-shuffle steps within the 16-lane row group.
#pragma unroll
    for (int i = 0; i < 2; ++i)
#pragma unroll
        for (int r = 0; r < 4; ++r) {
#pragma unroll
            for (int m = 1; m < 16; m <<= 1)
                lsum[i][r] += __shfl_xor(lsum[i][r], m);
        }

    // Normalize into the wave's strip (f16), read back row-contiguous,
    // apply ablation mask, 16B coalesced stores.
    _Float16* Pf = (_Float16*)P;
#pragma unroll
    for (int i = 0; i < 2; ++i)
#pragma unroll
        for (int r = 0; r < 4; ++r) {
            float inv = 1.f / lsum[i][r];
#pragma unroll
            for (int j = 0; j < 4; ++j)
                Pf[(i * 16 + rq + r) * 72 + j * 16 + lrow] = (_Float16)(o[i][j][r] * inv);
        }
#pragma unroll
    for (int u = 0; u < 4; ++u) {
        int slot = u * 64 + lane;
        int ro = slot >> 3;                 // local query row 0..31
        int d8 = (slot & 7) * 8;
        f16x8 v = *(const f16x8*)&Pf[ro * 72 + d8];
        size_t g = (size_t)(b * SS + wq + ro) * SH + h * HD + d8;
        float4 ma = *(const float4*)(amask + g);
        float4 mb = *(const float4*)(amask + g + 4);
        f16x8 rs;
        rs[0] = (_Float16)((float)v[0] * ma.x);
        rs[1] = (_Float16)((float)v[1] * ma.y);
        rs[2] = (_Float16)((float)v[2] * ma.z);
        rs[3] = (_Float16)((float)v[3] * ma.w);
        rs[4] = (_Float16)((float)v[4] * mb.x);
        rs[5] = (_Float16)((float)v[5] * mb.y);
        rs[6] = (_Float16)((float)v[6] * mb.z);
        rs[7] = (_Float16)((float)v[7] * mb.w);
        *(f16x8*)(ctxg + g) = rs;
    }
}

extern "C" void kernel_launch(void* const* d_in, const int* in_sizes, int n_in,
                              void* d_out, int out_size, void* d_ws, size_t ws_size,
                              hipStream_t stream)
{
    const float* x     = (const float*)d_in[0];
    const float* xc    = (const float*)d_in[1];
    const float* amask = (const float*)d_in[2];
    const float* Wq    = (const float*)d_in[3];
    const float* Wk    = (const float*)d_in[4];
    const float* Wv    = (const float*)d_in[5];
    const float* Wo    = (const float*)d_in[6];
    const float* bo    = (const float*)d_in[7];
    float* out = (float*)d_out;

    const int M = SB * SS;                       // 8192
    const size_t BUF = (size_t)M * SH;           // 8.4M elems (16MB @ 2B)
    const size_t WBUF = (size_t)SH * SH;         // 1M elems (2MB @ 2B)
    _Float16* xh  = (_Float16*)d_ws;             // 16MB
    _Float16* xch = xh + BUF;                    // 16MB
    _Float16* Qh  = xch + BUF;                   // 16MB (ctx aliases)
    _Float16* Kh  = Qh + BUF;                    // 16MB
    unsigned short* Vt = (unsigned short*)(Kh + BUF);   // 16MB bf16 V^T
    _Float16* Wqh = (_Float16*)(Vt + BUF);       // 4 x 2MB weights => 88MB total
    _Float16* Wkh = Wqh + WBUF;
    _Float16* Wvh = Wkh + WBUF;
    _Float16* Woh = Wvh + WBUF;
    _Float16* ctx = Qh;

    const int total4 = 2 * (M * SH / 4) + 4 * (SH * SH / 4);
    hipLaunchKernelGGL(cvt_all, dim3(total4 / 256), dim3(256), 0, stream,
                       x, xc, Wq, Wk, Wv, Wo, xh, xch, Wqh, Wkh, Wvh, Woh);

    hipLaunchKernelGGL(gemm_qkv8, dim3(M / 128, SH / 256, 3), dim3(512), 0, stream,
                       xh, xch, Wqh, Wkh, Wvh, Qh, Kh, Vt);

    hipLaunchKernelGGL(attn5, dim3((SS / 256) * NH * SB), dim3(512), 0, stream,
                       Qh, Kh, Vt, amask, ctx);

    hipLaunchKernelGGL(gemm_o8, dim3(M / 128, SH / 256), dim3(512), 0, stream,
                       ctx, Woh, bo, out);
}

// Round 4
// 265.788 us; speedup vs baseline: 1.0230x; 1.0230x over previous
//
#include <hip/hip_runtime.h>
#include <hip/hip_bf16.h>
#include <cstddef>

#define SB 4
#define SS 2048
#define SH 1024
#define NH 16
#define HD 64
#define WIN 256

typedef __attribute__((ext_vector_type(8))) short bf16x8;
typedef __attribute__((ext_vector_type(8))) _Float16 f16x8;
typedef __attribute__((ext_vector_type(2))) __fp16 fp16v2;
typedef __attribute__((ext_vector_type(4))) float f32x4;

static __device__ __forceinline__ ushort2 pk_bf16(float a, float b) {
    __hip_bfloat162 h = __float22bfloat162_rn(make_float2(a, b));
    union { __hip_bfloat162 h2; ushort2 u2; } u;
    u.h2 = h;
    return u.u2;
}
static __device__ __forceinline__ unsigned short pk1(float a) {
    return pk_bf16(a, 0.f).x;
}

// Async global->LDS, 16B per lane. LDS dest is wave-uniform base + lane*16
// (m104/m108): pass the SAME lds pointer from every lane of a wave.
static __device__ __forceinline__ void async16(const void* gptr, void* lptr) {
    __builtin_amdgcn_global_load_lds(
        (const __attribute__((address_space(1))) unsigned int*)gptr,
        (__attribute__((address_space(3))) unsigned int*)lptr, 16, 0, 0);
}

// Compiler-only memory fence: stops hipcc moving LDS/global accesses across
// barrier points (s_barrier builtin is NOT a compiler fence).
#define CFENCE() asm volatile("" ::: "memory")

// All six fp32->f16 conversions in one launch.
__global__ __launch_bounds__(256) void cvt_all(
    const float* __restrict__ x,  const float* __restrict__ xc,
    const float* __restrict__ Wq, const float* __restrict__ Wk,
    const float* __restrict__ Wv, const float* __restrict__ Wo,
    _Float16* __restrict__ xh,  _Float16* __restrict__ xch,
    _Float16* __restrict__ Wqh, _Float16* __restrict__ Wkh,
    _Float16* __restrict__ Wvh, _Float16* __restrict__ Woh)
{
    const int I4 = SB * SS * SH / 4;       // 2^21
    const int W4 = SH * SH / 4;            // 2^18
    int idx = blockIdx.x * 256 + threadIdx.x;
    const float* src;
    _Float16* dst;
    int off;
    if (idx < I4) { src = x; dst = xh; off = idx; }
    else if (idx < 2 * I4) { src = xc; dst = xch; off = idx - I4; }
    else {
        int r = idx - 2 * I4;
        int wi = r >> 18;
        off = r & (W4 - 1);
        src = (wi == 0) ? Wq : (wi == 1) ? Wk : (wi == 2) ? Wv : Wo;
        dst = (wi == 0) ? Wqh : (wi == 1) ? Wkh : (wi == 2) ? Wvh : Woh;
    }
    float4 v = ((const float4*)src)[off];
    union { fp16v2 h[2]; uint2 u; } t;
    t.h[0] = __builtin_amdgcn_cvt_pkrtz(v.x, v.y);
    t.h[1] = __builtin_amdgcn_cvt_pkrtz(v.z, v.w);
    ((uint2*)dst)[off] = t.u;
}

// ---------------------------------------------------------------------------
// 2-phase GEMM core (merged from the 4-phase m201 port; BM=128, BN=256,
// BK=64). C[M,N] = A[M,K] @ W[N,K]^T, f16 operands, fp32 acc.
// 512 threads = 8 waves (2M x 4N), per-wave output 64x64 (4x4 fragments).
// LDS 96KB: A[2buf][128][64] + B[2buf][256][64] f16.
//
// WHY 2 phases: round-3 counters showed MfmaUtil=32% with 8 barriers/K-tile
// and only 8 MFMA per wave between barriers; per-tile time 3220cyc vs
// 1030cyc MFMA. Phase overhead is ~constant per barrier-pair (m201 at 16
// MFMA/phase = 62%). Merging to 2 phases (16 MFMA/phase, 4 barriers/tile)
// halves the overhead per MFMA. LDS traffic unchanged (16 b128/wave/tile).
//
// Bank-conflict swizzle (verified r3: conflicts 6.5M -> 196K): rows are
// 128B = 8 x 16B slots; element col ^= (lrow&7)<<3 on ds_read; inverse-
// permuted GLOBAL source col ((lane&7)^((lane>>3)&7))<<3 with linear
// gload_lds dest (both-sides-or-neither, rule #21).
//
// Phase layout per K-tile t (cur = t&1):
//  P1: ds_read A(t) all 4 m-frags x2ks (8 b128) + B(t) h0 (4 b128);
//      stage A(t+1) h0+h1 and B(t+1) h1   [all -> other buffer, >=2-barrier
//      write-after-read slack];
//      vmcnt(6) [retires B(t)h1 before P2 reads it]; bar; lgkm0;
//      16 MFMA (n-cols 0,1); bar.
//  P2: ds_read B(t) h1 (4 b128);
//      stage B(t+2) h0 [cur buffer h0; region's reads drained by P1's
//      lgkm0 + bar handshake];
//      bar; lgkm0; 16 MFMA (n-cols 2,3);
//      boundary vmcnt(4) [leaves B(t+1)h1 + B(t+2)h0 in flight; retires
//      A(t+1) and B(t+1)h0 for next P1's reads]; bar.
// Tail: t=NT-2 boundary vmcnt(2); t=NT-1 mid vmcnt(0), boundary vmcnt(0)
// (also drains all staging before the epilogue reuses smem).
// Prologue: A(0)+B(0)+B(1)h0 issued (8), vmcnt(2) leaves B(1)h0 in flight.
// Foreign loads interleaved by the compiler only make waits stricter (vmcnt
// waits on total outstanding), never looser -> safe.
// ---------------------------------------------------------------------------
static __device__ __forceinline__ void gemm8_core(
    const _Float16* __restrict__ A, const _Float16* __restrict__ W,
    int m0, int n0, unsigned short* __restrict__ smem, f32x4 (&acc)[4][4])
{
    const int K = SH;
    const int NT = K / 64;                 // 16 K-tiles
    const int tid = threadIdx.x;
    const int w = tid >> 6, lane = tid & 63;
    const int wm = (w >> 2) * 64;          // wave row origin (0/64)
    const int wn = (w & 3) * 64;           // wave col origin (0/64/128/192)
    const int lrow = lane & 15;
    const int lk8 = (lane >> 4) * 8;
    const int swz = (lrow & 7) << 3;       // element-XOR: slot ^= row&7

    // staging lane geometry: one issue = 8 rows x 128B per wave (1KB);
    // inverse-permuted source col so linear LDS dest + swizzled read match.
    const int srow = w * 8 + (lane >> 3);                          // 0..63
    const int scol = ((lane & 7) ^ ((lane >> 3) & 7)) << 3;        // src col elems
    const _Float16* aS = A + (size_t)(m0 + srow) * K + scol;
    const _Float16* bS = W + (size_t)(n0 + srow) * K + scol;

    auto stA = [&](int tile, int half) {   // A half = 64 rows = 1 issue
        async16(aS + (size_t)(half * 64) * K + tile * 64,
                smem + ((tile & 1) << 13) + half * 4096 + w * 512);
    };
    auto stB = [&](int tile, int half) {   // B half = 128 rows = 2 issues
        async16(bS + (size_t)(half * 128) * K + tile * 64,
                smem + 16384 + ((tile & 1) << 14) + half * 8192 + w * 512);
        async16(bS + (size_t)(half * 128 + 64) * K + tile * 64,
                smem + 16384 + ((tile & 1) << 14) + half * 8192 + 4096 + w * 512);
    };

    f16x8 a[4][2];        // full A column frags   [m][ks], live both phases
    f16x8 b[2][2];        // current B half frags  [n][ks]

    // Prologue: tile0 fully + tile1's B h0. vmcnt(2) => tile0 landed.
    stA(0, 0); stA(0, 1);
    stB(0, 0); stB(0, 1);
    stB(1, 0);
    asm volatile("s_waitcnt vmcnt(2)" ::: "memory");
    __builtin_amdgcn_s_barrier();
    CFENCE();

    for (int t = 0; t < NT; ++t) {
        const int cur = t & 1;
        unsigned short* LA = smem + (cur << 13);
        unsigned short* LB = smem + 16384 + (cur << 14);

        // ---- P1: read A(t) full + B(t)h0; stage A(t+1)+B(t+1)h1; MFMA n0-1
#pragma unroll
        for (int m = 0; m < 4; ++m)
#pragma unroll
            for (int ks = 0; ks < 2; ++ks)
                a[m][ks] = *(const f16x8*)(LA + (wm + m * 16 + lrow) * 64 + ((ks * 32 + lk8) ^ swz));
#pragma unroll
        for (int n = 0; n < 2; ++n)
#pragma unroll
            for (int ks = 0; ks < 2; ++ks)
                b[n][ks] = *(const f16x8*)(LB + (wn + n * 16 + lrow) * 64 + ((ks * 32 + lk8) ^ swz));
        if (t + 1 < NT) { stA(t + 1, 0); stA(t + 1, 1); stB(t + 1, 1); }
        CFENCE();
        if (t + 1 < NT) asm volatile("s_waitcnt vmcnt(6)" ::: "memory");
        else            asm volatile("s_waitcnt vmcnt(0)" ::: "memory");
        __builtin_amdgcn_s_barrier();
        CFENCE();
        asm volatile("s_waitcnt lgkmcnt(0)" ::: "memory");
        __builtin_amdgcn_s_setprio(1);
#pragma unroll
        for (int ks = 0; ks < 2; ++ks)
#pragma unroll
            for (int m = 0; m < 4; ++m)
#pragma unroll
                for (int n = 0; n < 2; ++n)
                    acc[m][n] = __builtin_amdgcn_mfma_f32_16x16x32_f16(a[m][ks], b[n][ks], acc[m][n], 0, 0, 0);
        __builtin_amdgcn_s_setprio(0);
        CFENCE();
        __builtin_amdgcn_s_barrier();
        CFENCE();

        // ---- P2: read B(t)h1; stage B(t+2)h0; MFMA n2-3; boundary vmcnt
#pragma unroll
        for (int n = 0; n < 2; ++n)
#pragma unroll
            for (int ks = 0; ks < 2; ++ks)
                b[n][ks] = *(const f16x8*)(LB + (wn + 32 + n * 16 + lrow) * 64 + ((ks * 32 + lk8) ^ swz));
        if (t + 2 < NT) stB(t + 2, 0);
        CFENCE();
        __builtin_amdgcn_s_barrier();
        CFENCE();
        asm volatile("s_waitcnt lgkmcnt(0)" ::: "memory");
        __builtin_amdgcn_s_setprio(1);
#pragma unroll
        for (int ks = 0; ks < 2; ++ks)
#pragma unroll
            for (int m = 0; m < 4; ++m)
#pragma unroll
                for (int n = 0; n < 2; ++n)
                    acc[m][2 + n] = __builtin_amdgcn_mfma_f32_16x16x32_f16(a[m][ks], b[n][ks], acc[m][2 + n], 0, 0, 0);
        __builtin_amdgcn_s_setprio(0);
        // Boundary: retire A(t+1)+B(t+1)h0, keep B(t+1)h1+B(t+2)h0 in flight.
        if (t < NT - 2)       asm volatile("s_waitcnt vmcnt(4)" ::: "memory");
        else if (t == NT - 2) asm volatile("s_waitcnt vmcnt(2)" ::: "memory");
        else                  asm volatile("s_waitcnt vmcnt(0)" ::: "memory");
        __builtin_amdgcn_s_barrier();
        CFENCE();
    }
    CFENCE();
}

// Fused Q/K/V projection GEMMs, 2-phase core. blockIdx.z picks {A, W, epilogue}.
// z=0: x@Wq -> Qh (f16); z=1: xc@Wk -> Kh (f16); z=2: xc@Wv -> Vt (bf16, C^T).
__global__ __launch_bounds__(512, 2) void gemm_qkv8(
    const _Float16* __restrict__ xh, const _Float16* __restrict__ xch,
    const _Float16* __restrict__ Wqh, const _Float16* __restrict__ Wkh,
    const _Float16* __restrict__ Wvh,
    _Float16* __restrict__ Qh, _Float16* __restrict__ Kh,
    unsigned short* __restrict__ Vt)
{
    __shared__ __align__(16) unsigned short smem[49152]; // 96KB
    const int z = blockIdx.z;
    const _Float16* A = (z == 0) ? xh : xch;
    const _Float16* W = (z == 0) ? Wqh : (z == 1) ? Wkh : Wvh;
    const int m0 = blockIdx.x * 128;
    const int n0 = blockIdx.y * 256;

    f32x4 acc[4][4];
#pragma unroll
    for (int i = 0; i < 4; ++i)
#pragma unroll
        for (int j = 0; j < 4; ++j)
            acc[i][j] = (f32x4){0.f, 0.f, 0.f, 0.f};

    gemm8_core(A, W, m0, n0, smem, acc);

    const int tid = threadIdx.x;
    const int w = tid >> 6, lane = tid & 63;
    const int wm = (w >> 2) * 64, wn = (w & 3) * 64;
    const int lrow = lane & 15;
    const int rq = (lane >> 4) * 4;
    const int M = SB * SS, N = SH;

    // C/D layout: col = lane&15, row = (lane>>4)*4 + reg.
    if (z < 2) {
        // f16 out via full-tile LDS transpose (128 x 264) -> b128 stores.
        _Float16* C = (z == 0) ? Qh : Kh;
        _Float16* T = (_Float16*)smem;
#pragma unroll
        for (int m = 0; m < 4; ++m)
#pragma unroll
            for (int n = 0; n < 4; ++n)
#pragma unroll
                for (int r = 0; r < 4; ++r)
                    T[(wm + m * 16 + rq + r) * 264 + wn + n * 16 + lrow] = (_Float16)acc[m][n][r];
        __syncthreads();
#pragma unroll
        for (int u = 0; u < 8; ++u) {
            int slot = u * 512 + tid;              // 4096 uint4 slots
            int row = slot >> 5;
            int c8 = (slot & 31) * 8;
            *(uint4*)(C + (size_t)(m0 + row) * N + n0 + c8) =
                *(const uint4*)&T[row * 264 + c8];
        }
    } else {
        // Transposed bf16 out via LDS (256 x 136 shorts), single pass.
        unsigned short* T = smem;
#pragma unroll
        for (int n = 0; n < 4; ++n)
#pragma unroll
            for (int m = 0; m < 4; ++m) {
                int rt = wn + n * 16 + lrow;
                *(ushort4*)&T[rt * 136 + wm + m * 16 + rq] = make_ushort4(
                    pk1(acc[m][n][0]), pk1(acc[m][n][1]),
                    pk1(acc[m][n][2]), pk1(acc[m][n][3]));
            }
        __syncthreads();
#pragma unroll
        for (int u = 0; u < 8; ++u) {
            int slot = u * 512 + tid;              // 4096 uint4 slots
            int row = slot >> 4;
            int m8 = (slot & 15) * 8;
            *(uint4*)(Vt + (size_t)(n0 + row) * M + m0 + m8) =
                *(const uint4*)&T[row * 136 + m8];
        }
    }
}

// O-projection GEMM: ctx(f16) @ Wo^T + bo -> out (fp32), 2-phase core,
// direct fp32 stores (4x64B segments per instr).
__global__ __launch_bounds__(512, 2) void gemm_o8(
    const _Float16* __restrict__ A, const _Float16* __restrict__ W,
    const float* __restrict__ bias, float* __restrict__ C)
{
    __shared__ __align__(16) unsigned short smem[49152]; // 96KB
    const int m0 = blockIdx.x * 128;
    const int n0 = blockIdx.y * 256;

    f32x4 acc[4][4];
#pragma unroll
    for (int i = 0; i < 4; ++i)
#pragma unroll
        for (int j = 0; j < 4; ++j)
            acc[i][j] = (f32x4){0.f, 0.f, 0.f, 0.f};

    gemm8_core(A, W, m0, n0, smem, acc);

    const int tid = threadIdx.x;
    const int w = tid >> 6, lane = tid & 63;
    const int wm = (w >> 2) * 64, wn = (w & 3) * 64;
    const int lrow = lane & 15;
    const int rq = (lane >> 4) * 4;
    const int N = SH;

#pragma unroll
    for (int m = 0; m < 4; ++m) {
        int rbase = m0 + wm + m * 16 + rq;
#pragma unroll
        for (int n = 0; n < 4; ++n) {
            int col = n0 + wn + n * 16 + lrow;
            float badd = bias[col];
#pragma unroll
            for (int r = 0; r < 4; ++r)
                C[(size_t)(rbase + r) * N + col] = acc[m][n][r] + badd;
        }
    }
}

// MFMA flash attention, local causal window. Block = 8 waves = 256 queries of
// one (b,h): halves barriers and K/V staging per query vs 128-query blocks.
// Double-buffered K/V chunks (stage c+1 during compute of c); waves skip
// chunks outside their 287-key window (wave-uniform branch). 1-D grid with
// id%8 == (h,b)-pair%8 so all qb-blocks of one (b,h) share one XCD's L2
// (K+V per pair = 512KB; 8 pairs/XCD = 4MB = L2 size). P,V bf16 (exp(s) up
// to ~e^47 needs bf16 range; no online max since fp32 can't overflow).
// ctx may alias Qg: each wave reads exactly the 32 Q rows it later writes,
// reads happen before any write, rows are wave-exclusive -> race-free.
__global__ __launch_bounds__(512, 4) void attn5(
    const _Float16* Qg, const _Float16* __restrict__ Kg,
    const unsigned short* __restrict__ Vtg, const float* __restrict__ amask,
    _Float16* ctxg)
{
    __shared__ __align__(16) _Float16 K_s[2][2 * 64 * 32];        // 16KB [buf][ki][key][32d]
    __shared__ __align__(16) unsigned short V_s[2][2 * 64 * 32];  // 16KB [buf][ki][d][32key]
    __shared__ __align__(16) unsigned short P_s[8][32 * 72];      // 36.9KB per-wave strips

    const int t = threadIdx.x;
    const int wave = t >> 6, lane = t & 63;
    const int id = blockIdx.x;        // 512 blocks
    const int qb = id >> 6;           // 0..7
    const int pr = id & 63;           // (h,b) pair; id%8 = pr%8 -> XCD grouping
    const int h = pr & 15, b = pr >> 4;
    const int t0 = qb * 256;
    const int wq = t0 + wave * 32;    // this wave's first query
    const int lrow = lane & 15;
    const int lk8 = (lane >> 4) * 8;
    const int rq = (lane >> 4) * 4;
    const int M = SB * SS;
    unsigned short* P = P_s[wave];

    // Staging decomposition: 512 threads x 16B = one full 8KB chunk per array.
    const int ski = t >> 8;           // ki half
    const int srow = (t & 255) >> 2;  // key row (K) / d row (Vt)
    const int se8 = (t & 3) * 8;

    // Q A-fragments in registers (wave-private rows).
    f16x8 qf[2][2];
#pragma unroll
    for (int i = 0; i < 2; ++i)
#pragma unroll
        for (int ki = 0; ki < 2; ++ki)
            qf[i][ki] = *(const f16x8*)(Qg +
                (size_t)(b * SS + wq + i * 16 + lrow) * SH + h * HD + ki * 32 + lk8);

    f32x4 o[2][4];
    float lsum[2][4];
#pragma unroll
    for (int i = 0; i < 2; ++i)
#pragma unroll
        for (int j = 0; j < 4; ++j) o[i][j] = (f32x4){0.f, 0.f, 0.f, 0.f};
#pragma unroll
    for (int i = 0; i < 2; ++i)
#pragma unroll
        for (int r = 0; r < 4; ++r) lsum[i][r] = 0.f;

    int cl0 = t0 - (WIN - 1);
    cl0 = cl0 < 0 ? 0 : cl0;
    const int c_lo = cl0 >> 6;
    const int c_hi = (t0 >> 6) + 3;   // keys up to t0+255

    auto stage = [&](int c, int buf) {
        const int key0 = c * 64;
        async16(Kg + (size_t)(b * SS + key0 + srow) * SH + h * HD + ski * 32 + se8,
                (_Float16*)K_s[buf] + wave * 512);
        async16(Vtg + (size_t)(h * HD + srow) * M + b * SS + key0 + ski * 32 + se8,
                (unsigned short*)V_s[buf] + wave * 512);
    };

    stage(c_lo, c_lo & 1);
    __syncthreads();

    for (int c = c_lo; c <= c_hi; ++c) {
        const int cur = c & 1;
        if (c < c_hi) stage(c + 1, cur ^ 1);     // flies during compute below
        const int key0 = c * 64;
        // Wave-uniform skip: does chunk intersect this wave's key window?
        if (key0 <= wq + 31 && key0 + 63 >= wq - (WIN - 1)) {
            const _Float16* Kc = (const _Float16*)K_s[cur];
            const unsigned short* Vc = (const unsigned short*)V_s[cur];

            // S = Q @ K^T
            f32x4 s[2][4];
#pragma unroll
            for (int i = 0; i < 2; ++i)
#pragma unroll
                for (int j = 0; j < 4; ++j) s[i][j] = (f32x4){0.f, 0.f, 0.f, 0.f};
#pragma unroll
            for (int ki = 0; ki < 2; ++ki)
#pragma unroll
                for (int j = 0; j < 4; ++j) {
                    f16x8 bh = *(const f16x8*)&Kc[ki * 2048 + (j * 16 + lrow) * 32 + lk8];
#pragma unroll
                    for (int i = 0; i < 2; ++i)
                        s[i][j] = __builtin_amdgcn_mfma_f32_16x16x32_f16(qf[i][ki], bh, s[i][j], 0, 0, 0);
                }

            // mask + exp (fp32), row-sum partials, P -> bf16 LDS (A-layout rows).
#pragma unroll
            for (int i = 0; i < 2; ++i)
#pragma unroll
                for (int j = 0; j < 4; ++j) {
                    int jg = key0 + j * 16 + lrow;
#pragma unroll
                    for (int r = 0; r < 4; ++r) {
                        int qg = wq + i * 16 + rq + r;
                        float p = (jg <= qg && jg > qg - WIN) ? __expf(s[i][j][r]) : 0.f;
                        lsum[i][r] += p;
                        P[(i * 16 + rq + r) * 72 + j * 16 + lrow] = pk1(p);
                    }
                }

            // ctx += P @ V (in-wave LDS dependency only)
#pragma unroll
            for (int ki = 0; ki < 2; ++ki) {
                bf16x8 pf[2];
#pragma unroll
                for (int i = 0; i < 2; ++i)
                    pf[i] = *(const bf16x8*)&P[(i * 16 + lrow) * 72 + ki * 32 + lk8];
#pragma unroll
                for (int j = 0; j < 4; ++j) {
                    bf16x8 vf = *(const bf16x8*)&Vc[ki * 2048 + (j * 16 + lrow) * 32 + lk8];
#pragma unroll
                    for (int i = 0; i < 2; ++i)
                        o[i][j] = __builtin_amdgcn_mfma_f32_16x16x32_bf16(pf[i], vf, o[i][j], 0, 0, 0);
                }
            }
        }
        __syncthreads();   // guards buffers; drains in-flight staging
    }

    // Row sums: 4 xor-shuffle steps within the 16-lane row group.
#pragma unroll
    for (int i = 0; i < 2; ++i)
#pragma unroll
        for (int r = 0; r < 4; ++r) {
#pragma unroll
            for (int m = 1; m < 16; m <<= 1)
                lsum[i][r] += __shfl_xor(lsum[i][r], m);
        }

    // Normalize into the wave's strip (f16), read back row-contiguous,
    // apply ablation mask, 16B coalesced stores.
    _Float16* Pf = (_Float16*)P;
#pragma unroll
    for (int i = 0; i < 2; ++i)
#pragma unroll
        for (int r = 0; r < 4; ++r) {
            float inv = 1.f / lsum[i][r];
#pragma unroll
            for (int j = 0; j < 4; ++j)
                Pf[(i * 16 + rq + r) * 72 + j * 16 + lrow] = (_Float16)(o[i][j][r] * inv);
        }
#pragma unroll
    for (int u = 0; u < 4; ++u) {
        int slot = u * 64 + lane;
        int ro = slot >> 3;                 // local query row 0..31
        int d8 = (slot & 7) * 8;
        f16x8 v = *(const f16x8*)&Pf[ro * 72 + d8];
        size_t g = (size_t)(b * SS + wq + ro) * SH + h * HD + d8;
        float4 ma = *(const float4*)(amask + g);
        float4 mb = *(const float4*)(amask + g + 4);
        f16x8 rs;
        rs[0] = (_Float16)((float)v[0] * ma.x);
        rs[1] = (_Float16)((float)v[1] * ma.y);
        rs[2] = (_Float16)((float)v[2] * ma.z);
        rs[3] = (_Float16)((float)v[3] * ma.w);
        rs[4] = (_Float16)((float)v[4] * mb.x);
        rs[5] = (_Float16)((float)v[5] * mb.y);
        rs[6] = (_Float16)((float)v[6] * mb.z);
        rs[7] = (_Float16)((float)v[7] * mb.w);
        *(f16x8*)(ctxg + g) = rs;
    }
}

extern "C" void kernel_launch(void* const* d_in, const int* in_sizes, int n_in,
                              void* d_out, int out_size, void* d_ws, size_t ws_size,
                              hipStream_t stream)
{
    const float* x     = (const float*)d_in[0];
    const float* xc    = (const float*)d_in[1];
    const float* amask = (const float*)d_in[2];
    const float* Wq    = (const float*)d_in[3];
    const float* Wk    = (const float*)d_in[4];
    const float* Wv    = (const float*)d_in[5];
    const float* Wo    = (const float*)d_in[6];
    const float* bo    = (const float*)d_in[7];
    float* out = (float*)d_out;

    const int M = SB * SS;                       // 8192
    const size_t BUF = (size_t)M * SH;           // 8.4M elems (16MB @ 2B)
    const size_t WBUF = (size_t)SH * SH;         // 1M elems (2MB @ 2B)
    _Float16* xh  = (_Float16*)d_ws;             // 16MB
    _Float16* xch = xh + BUF;                    // 16MB
    _Float16* Qh  = xch + BUF;                   // 16MB (ctx aliases)
    _Float16* Kh  = Qh + BUF;                    // 16MB
    unsigned short* Vt = (unsigned short*)(Kh + BUF);   // 16MB bf16 V^T
    _Float16* Wqh = (_Float16*)(Vt + BUF);       // 4 x 2MB weights => 88MB total
    _Float16* Wkh = Wqh + WBUF;
    _Float16* Wvh = Wkh + WBUF;
    _Float16* Woh = Wvh + WBUF;
    _Float16* ctx = Qh;

    const int total4 = 2 * (M * SH / 4) + 4 * (SH * SH / 4);
    hipLaunchKernelGGL(cvt_all, dim3(total4 / 256), dim3(256), 0, stream,
                       x, xc, Wq, Wk, Wv, Wo, xh, xch, Wqh, Wkh, Wvh, Woh);

    hipLaunchKernelGGL(gemm_qkv8, dim3(M / 128, SH / 256, 3), dim3(512), 0, stream,
                       xh, xch, Wqh, Wkh, Wvh, Qh, Kh, Vt);

    hipLaunchKernelGGL(attn5, dim3((SS / 256) * NH * SB), dim3(512), 0, stream,
                       Qh, Kh, Vt, amask, ctx);

    hipLaunchKernelGGL(gemm_o8, dim3(M / 128, SH / 256), dim3(512), 0, stream,
                       ctx, Woh, bo, out);
}